// Round 4
// baseline (359.026 us; speedup 1.0000x reference)
//
#include <hip/hip_runtime.h>

#define B 2
#define N 768
#define DIM 512
#define DE 64
#define LN_EPS 1e-5f

typedef float f32x4 __attribute__((ext_vector_type(4)));

// Workspace layout (floats):
//   Cc  : [B*N*DE]      centered C = (x W_c^T) W_e^T - mean
//   ssqC: [B*N]         sum(Cc^2) per token
#define OFF_CC   0
#define OFF_SSC  (B*N*DE)

// Kernel A: cols only, 2 tokens per block (768 blocks, 256 thr).
// Each wave owns 16 f-outputs; one W_c row load feeds BOTH tokens' dots
// (ILP-2 on the shfl trees, W L2 traffic halved).
__global__ __launch_bounds__(256) void ee_cols(
    const float* __restrict__ x, const float* __restrict__ Wc,
    const float* __restrict__ We,
    float* __restrict__ Cc, float* __restrict__ ssqC)
{
    __shared__ float xs[2 * DIM];
    __shared__ float cc[2 * DE];

    const int tok0 = blockIdx.x * 2;
    const int tid = threadIdx.x;
    const int lane = tid & 63;
    const int wave = tid >> 6;

    const float* xp = x + (size_t)tok0 * DIM;
    xs[tid]       = xp[tid];
    xs[tid + 256] = xp[tid + 256];
    xs[tid + 512] = xp[tid + 512];
    xs[tid + 768] = xp[tid + 768];
    __syncthreads();

    const float4 b00 = *(const float4*)(xs + lane * 8);
    const float4 b01 = *(const float4*)(xs + lane * 8 + 4);
    const float4 b10 = *(const float4*)(xs + DIM + lane * 8);
    const float4 b11 = *(const float4*)(xs + DIM + lane * 8 + 4);

    for (int m = 0; m < 16; ++m) {
        const int f = wave * 16 + m;
        const float* W = Wc + (size_t)f * DIM;
        const float4 a0 = *(const float4*)(W + lane * 8);
        const float4 a1 = *(const float4*)(W + lane * 8 + 4);
        float p0 = a0.x*b00.x + a0.y*b00.y + a0.z*b00.z + a0.w*b00.w
                 + a1.x*b01.x + a1.y*b01.y + a1.z*b01.z + a1.w*b01.w;
        float p1 = a0.x*b10.x + a0.y*b10.y + a0.z*b10.z + a0.w*b10.w
                 + a1.x*b11.x + a1.y*b11.y + a1.z*b11.z + a1.w*b11.w;
        #pragma unroll
        for (int s = 1; s < 64; s <<= 1) {
            p0 += __shfl_xor(p0, s);
            p1 += __shfl_xor(p1, s);
        }
        if (lane == 0) { cc[f] = p0; cc[DE + f] = p1; }
    }
    __syncthreads();

    // Transform + center + ssq: wave 0 -> token 0, wave 1 -> token 1.
    if (tid < 128) {
        const int t = wave;
        const int f = lane;
        const float* W = We + (size_t)f * DE;
        const float* ccp = cc + t * DE;
        float acc = 0.f;
        #pragma unroll
        for (int e4 = 0; e4 < DE / 4; ++e4) {
            const float4 w4 = *(const float4*)(W + e4 * 4);
            const float4 r4 = *(const float4*)(ccp + e4 * 4);
            acc += w4.x*r4.x + w4.y*r4.y + w4.z*r4.z + w4.w*r4.w;
        }
        float mu = acc;
        #pragma unroll
        for (int s = 1; s < 64; s <<= 1) mu += __shfl_xor(mu, s);
        mu *= (1.f / DE);
        const float c = acc - mu;
        float sq = c * c;
        #pragma unroll
        for (int s = 1; s < 64; s <<= 1) sq += __shfl_xor(sq, s);
        Cc[(size_t)(tok0 + t) * DE + f] = c;
        if (lane == 0) ssqC[tok0 + t] = sq;
    }
}

// Kernel B: one block per (b,i) row. Short prefix computes this row's
// Rc_i (rows dot + We transform + center/ssq) — hidden under other
// blocks' BW-bound store phases — then scales + streaming output.
__global__ __launch_bounds__(256) void ee_rows_ln(
    const float* __restrict__ x, const float* __restrict__ Wr,
    const float* __restrict__ We,
    const float* __restrict__ Cc, const float* __restrict__ ssqCp,
    const float* __restrict__ gamma, const float* __restrict__ beta,
    float* __restrict__ out)
{
    __shared__ float xs[DIM];
    __shared__ float rr[DE];     // raw rows (pre-transform)
    __shared__ float rs[DE];     // centered Rc_i
    __shared__ float sj[N];      // rsqrt scale per j
    __shared__ float ssqR_s;

    const int bi = blockIdx.x;               // b*N + i
    const int tid = threadIdx.x;
    const int lane = tid & 63;
    const int wave = tid >> 6;
    const int jsub = lane >> 4;
    const int fb = (lane & 15) * 4;

    const int b = bi / N;
    const float* Ccb   = Cc + (size_t)b * N * DE;
    const float* ssqCb = ssqCp + (size_t)b * N;
    float* outb = out + (size_t)bi * N * DE;

    // Prefix 1: stage x_i, compute 64 row-dots (wave w owns f = w*16..+15).
    const float* xp = x + (size_t)bi * DIM;
    xs[tid]       = xp[tid];
    xs[tid + 256] = xp[tid + 256];
    __syncthreads();

    const float4 b0 = *(const float4*)(xs + lane * 8);
    const float4 b1 = *(const float4*)(xs + lane * 8 + 4);
    for (int m = 0; m < 16; ++m) {
        const int o = wave * 16 + m;
        const float* W = Wr + (size_t)o * DIM;
        const float4 a0 = *(const float4*)(W + lane * 8);
        const float4 a1 = *(const float4*)(W + lane * 8 + 4);
        float p = a0.x*b0.x + a0.y*b0.y + a0.z*b0.z + a0.w*b0.w
                + a1.x*b1.x + a1.y*b1.y + a1.z*b1.z + a1.w*b1.w;
        #pragma unroll
        for (int s = 1; s < 64; s <<= 1) p += __shfl_xor(p, s);
        if (lane == 0) rr[o] = p;
    }
    __syncthreads();

    // Prefix 2: wave 0 does We transform + center + ssq.
    if (tid < 64) {
        const float* W = We + (size_t)tid * DE;
        float acc = 0.f;
        #pragma unroll
        for (int e4 = 0; e4 < DE / 4; ++e4) {
            const float4 w4 = *(const float4*)(W + e4 * 4);
            const float4 r4 = *(const float4*)(rr + e4 * 4);
            acc += w4.x*r4.x + w4.y*r4.y + w4.z*r4.z + w4.w*r4.w;
        }
        float mu = acc;
        #pragma unroll
        for (int s = 1; s < 64; s <<= 1) mu += __shfl_xor(mu, s);
        mu *= (1.f / DE);
        const float c = acc - mu;
        float sq = c * c;
        #pragma unroll
        for (int s = 1; s < 64; s <<= 1) sq += __shfl_xor(sq, s);
        rs[tid] = c;
        if (tid == 0) ssqR_s = sq;
    }
    __syncthreads();

    const float ssqR = ssqR_s;

    // Phase 1: per-thread dot(Rc_i, Cc_j); scales into LDS. No cross-lane ops.
    #pragma unroll
    for (int jt = 0; jt < N / 256; ++jt) {
        const int j0 = jt * 256 + tid;
        const float* cj = Ccb + (size_t)j0 * DE;
        f32x4 a = (f32x4)(0.f);
        #pragma unroll
        for (int e = 0; e < DE / 4; ++e) {
            const f32x4 w = *(const f32x4*)(rs + e * 4);
            const f32x4 c = *(const f32x4*)(cj + e * 4);
            a += w * c;
        }
        const float p = a.x + a.y + a.z + a.w;
        const float var = (ssqR + ssqCb[j0] + 2.f * p) * (1.f / DE);
        sj[j0] = rsqrtf(var + LN_EPS);
    }
    __syncthreads();

    // Per-lane constants for the streaming phase.
    const f32x4 r  = *(const f32x4*)(rs + fb);
    const f32x4 g  = *(const f32x4*)(gamma + fb);
    const f32x4 be = *(const f32x4*)(beta + fb);

    // Phase 2: streaming writes. Wave covers j = t*16 + wave*4 + jsub,
    // lane quad covers f = fb..fb+3. All iterations independent.
    #pragma unroll 4
    for (int t = 0; t < N / 16; ++t) {
        const int j = t * 16 + wave * 4 + jsub;
        const f32x4 c = *(const f32x4*)(Ccb + (size_t)j * DE + fb);
        const float s = sj[j];
        f32x4 o = (r + c) * (s * g) + be;
        __builtin_nontemporal_store(o, (f32x4*)(outb + (size_t)j * DE + fb));
    }
}

extern "C" void kernel_launch(void* const* d_in, const int* in_sizes, int n_in,
                              void* d_out, int out_size, void* d_ws, size_t ws_size,
                              hipStream_t stream) {
    const float* x     = (const float*)d_in[0];
    const float* Wr    = (const float*)d_in[1];
    const float* Wc    = (const float*)d_in[2];
    const float* We    = (const float*)d_in[3];
    const float* gamma = (const float*)d_in[4];
    const float* beta  = (const float*)d_in[5];
    float* out = (float*)d_out;
    float* ws  = (float*)d_ws;

    float* Cc   = ws + OFF_CC;
    float* ssqC = ws + OFF_SSC;

    ee_cols<<<B * N / 2, 256, 0, stream>>>(x, Wc, We, Cc, ssqC);
    ee_rows_ln<<<B * N, 256, 0, stream>>>(x, Wr, We, Cc, ssqC, gamma, beta, out);
}